// Round 7
// baseline (2265.918 us; speedup 1.0000x reference)
//
#include <hip/hip_runtime.h>
#include <stdint.h>

// R11 = R10 with the timeout amplifier removed (poll guard 1<<17 -> 1024).
// TreeRNN T=256, D=512, H=E=256, V=8192.
// Barrier-free free-running waves on R4/R9's proven LLC exchange protocol.
//   grid 256 x 256thr = 32 groups (16 rows) x 8 slices (32 cols); block = 4
//   waves (gru x col-half) but waves NEVER sync intra-block in the loop:
//   - h A-fragments gathered DIRECTLY into registers from the exchange buffer
//     (agent-relaxed u64 loads, own row l16) -- no LDS staging, no barriers.
//   - x A-fragments loaded directly from emb (L2-resident), ih-GEMM computed
//     AFTER publish (off the critical chain), result carried in registers.
//   - fp32 state carry in LDS hold[2][16][33] double-buffered; reads happen
//     after the poll, which transitively orders the pair-wave's write
//     (write -> waitcnt(0) -> flag -> [LLC] -> my poll -> my read). The
//     2-step buffer reuse distance makes WAR impossible: a wave writes
//     buf[(t+1)&1] only after poll(t), which requires every wave's flag t,
//     set only after that wave's read of buf[(t-1)&1] completed.
//   - publish: agent stores -> s_waitcnt(0) (vm+lgkm) -> relaxed per-wave
//     flag; poll 32 flags w/ ballot + s_sleep; guard 1024 (legit skew is
//     ~15-50 iters; broken sync bails in ~0.15 ms/step -> visible failure,
//     never a container-killing hang).
// Numerics identical to R4/R9: bf16 exchange (RNE) for MFMA-A, fp32 carry.

#define TT   256
#define DDIM 512
#define GUARD_ITERS 1024

typedef float    float4v __attribute__((ext_vector_type(4)));
typedef short    short8  __attribute__((ext_vector_type(8)));
typedef uint32_t uint4v  __attribute__((ext_vector_type(4)));

__device__ __forceinline__ unsigned short f2bf(float f){
  uint32_t u = __float_as_uint(f);
  u += 0x7fffu + ((u >> 16) & 1u);          // RNE, finite inputs
  return (unsigned short)(u >> 16);
}
__device__ __forceinline__ float bf2f(unsigned short h){
  return __uint_as_float(((uint32_t)h) << 16);
}
__device__ __forceinline__ float4v splat4(float v){ return (float4v){v, v, v, v}; }

union FragU { short8 v; uint64_t q[2]; };

__global__ __launch_bounds__(256, 1)
void treernn_main(const int* __restrict__ nodes,
                  const unsigned char* __restrict__ edges,
                  const unsigned char* __restrict__ hinit,
                  const unsigned char* __restrict__ emb,
                  const unsigned char* __restrict__ cWih, const unsigned char* __restrict__ cWhh,
                  const unsigned char* __restrict__ cbih, const unsigned char* __restrict__ cbhh,
                  const unsigned char* __restrict__ sWih, const unsigned char* __restrict__ sWhh,
                  const unsigned char* __restrict__ sbih, const unsigned char* __restrict__ sbhh,
                  unsigned char* __restrict__ out,
                  unsigned char* __restrict__ ws)
{
  __shared__ float hold[2][16 * 33];   // fp32 carry, double-buffered (barrier-free)
  __shared__ int det[8];

  const int tid  = threadIdx.x;
  const int lane = tid & 63;
  const int wv   = tid >> 6;
  const int gru  = wv >> 1;         // 0 = child GRU, 1 = sibling GRU
  const int ch   = wv & 1;          // 16-col half of the 32-col slice
  const int quad = lane >> 4;
  const int l16  = lane & 15;
  const int bid  = blockIdx.x;

  const int G    = bid >> 3;        // group: rows [G*16, +16), 32 groups
  const int cs   = bid & 7;         // col-slice: cols [cs*32, +32)
  const int d0   = G * 16;
  const int colw = ch * 16 + l16;   // col within slice (hold index)
  const int col  = cs * 32 + colw;  // global h-col (C/D col)
  const int myrow = d0 + l16;       // A-fragment row for this lane

  // ---------------- runtime dtype detection (R4 verbatim) ----------------
  if (tid < 8) det[tid] = 0;
  __syncthreads();
  {
    const unsigned short* hu = (const unsigned short*)hinit;
    int ce = 0;
    for (int i = tid; i < 4096; i += 256){
      const int e = (hu[i] >> 7) & 0xFF;
      ce += (e >= 100 && e <= 130) ? 1 : 0;
    }
    atomicAdd(&det[0], ce);
    const uint32_t* ewp = (const uint32_t*)edges;
    int b01 = 0, w01 = 0, wf = 0, hb = 0;
    for (int i = tid; i < 512; i += 256){
      const uint32_t w = ewp[i];
      w01 += (w <= 1u) ? 1 : 0;
      wf  += (w == 0u || w == 0x3F800000u) ? 1 : 0;
      const uint32_t h0 = w & 0xFFFFu, h1 = w >> 16;
      hb  += ((h0 == 0u || h0 == 0x3F80u) ? 1 : 0) + ((h1 == 0u || h1 == 0x3F80u) ? 1 : 0);
      b01 += (((w      ) & 0xFFu) <= 1u ? 1 : 0) + (((w >> 8 ) & 0xFFu) <= 1u ? 1 : 0)
           + (((w >> 16) & 0xFFu) <= 1u ? 1 : 0) + (((w >> 24)        ) <= 1u ? 1 : 0);
    }
    atomicAdd(&det[1], b01); atomicAdd(&det[2], w01);
    atomicAdd(&det[3], wf);  atomicAdd(&det[4], hb);
  }
  __syncthreads();
  const int fdt = (det[0] >= 3480) ? 1 : 0;   // 1 = floats are bf16
  int efmt;                                    // 0=u8, 1=i32, 2=f32, 3=bf16
  if      (det[2] == 512)  efmt = 1;
  else if (det[1] == 2048) efmt = 0;
  else if (det[4] == 1024) efmt = 3;
  else if (det[3] == 512)  efmt = 2;
  else                     efmt = 0;

  uint32_t*       flg = (uint32_t*)ws;                 // [32 groups][32 wave-flags]
  unsigned short* xbp = (unsigned short*)(ws + 16384); // [2][512][256] bf16 exchange

  const unsigned char* Wihp = gru ? sWih : cWih;
  const unsigned char* Whhp = gru ? sWhh : cWhh;
  const unsigned char* bihp = gru ? sbih : cbih;
  const unsigned char* bhhp = gru ? sbhh : cbhh;

  float bI[3], bH[3];
  #pragma unroll
  for (int ga = 0; ga < 3; ++ga){
    if (fdt){
      bI[ga] = bf2f(((const unsigned short*)bihp)[ga * 256 + col]);
      bH[ga] = bf2f(((const unsigned short*)bhhp)[ga * 256 + col]);
    } else {
      bI[ga] = ((const float*)bihp)[ga * 256 + col];
      bH[ga] = ((const float*)bhhp)[ga * 256 + col];
    }
  }

  // Weight slices -> bf16 MFMA B-fragments (proven layout: B[k=quad*8+j][n=l16])
  short8 wI[3][8], wH[3][8];
  for (int ga = 0; ga < 3; ++ga){
    const int rw = ga * 256 + col;
    for (int kc = 0; kc < 8; ++kc){
      const int ke = kc * 32 + quad * 8;
      if (fdt){
        wI[ga][kc] = *(const short8*)((const unsigned short*)Wihp + (size_t)rw * 256 + ke);
        wH[ga][kc] = *(const short8*)((const unsigned short*)Whhp + (size_t)rw * 256 + ke);
      } else {
        const float* pI = (const float*)Wihp + (size_t)rw * 256 + ke;
        const float* pH = (const float*)Whhp + (size_t)rw * 256 + ke;
        short8 va, vb;
        #pragma unroll
        for (int j = 0; j < 8; ++j){ va[j] = (short)f2bf(pI[j]); vb[j] = (short)f2bf(pH[j]); }
        wI[ga][kc] = va; wH[ga][kc] = vb;
      }
    }
  }

  // ---------------- preloop: gi_0 (x_0 ih-GEMM), h_0 frags, hold init, ef_0 ----------------
  short8 frag[8];            // shared buffer: x-frags, then h-frags (non-overlapping lifetimes)
  float4v gi[3];

  { // x_0 A-frags from emb row nodes[myrow], then ih-GEMM -> gi
    const int nd = nodes[myrow];
    if (fdt){
      const unsigned short* p16 = (const unsigned short*)emb + (size_t)nd * 256 + quad * 8;
      #pragma unroll
      for (int kc = 0; kc < 8; ++kc) frag[kc] = *(const short8*)(p16 + kc * 32);
    } else {
      const float* p32 = (const float*)emb + (size_t)nd * 256 + quad * 8;
      #pragma unroll
      for (int kc = 0; kc < 8; ++kc){
        uint4v a = *(const uint4v*)(p32 + kc * 32);
        uint4v b = *(const uint4v*)(p32 + kc * 32 + 4);
        short8 v;
        #pragma unroll
        for (int j = 0; j < 4; ++j){ v[j] = (short)f2bf(__uint_as_float(a[j]));
                                     v[4 + j] = (short)f2bf(__uint_as_float(b[j])); }
        frag[kc] = v;
      }
    }
    #pragma unroll
    for (int ga = 0; ga < 3; ++ga) gi[ga] = splat4(bI[ga]);
    #pragma unroll
    for (int kc = 0; kc < 8; ++kc){
      #pragma unroll
      for (int ga = 0; ga < 3; ++ga)
        gi[ga] = __builtin_amdgcn_mfma_f32_16x16x32_bf16(frag[kc], wI[ga][kc], gi[ga], 0, 0, 0);
    }
  }

  { // h_0 A-frags from hinit row myrow (frag[] reused)
    if (fdt){
      const unsigned short* p16 = (const unsigned short*)hinit + (size_t)myrow * 256 + quad * 8;
      #pragma unroll
      for (int kc = 0; kc < 8; ++kc) frag[kc] = *(const short8*)(p16 + kc * 32);
    } else {
      const float* p32 = (const float*)hinit + (size_t)myrow * 256 + quad * 8;
      #pragma unroll
      for (int kc = 0; kc < 8; ++kc){
        uint4v a = *(const uint4v*)(p32 + kc * 32);
        uint4v b = *(const uint4v*)(p32 + kc * 32 + 4);
        short8 v;
        #pragma unroll
        for (int j = 0; j < 4; ++j){ v[j] = (short)f2bf(__uint_as_float(a[j]));
                                     v[4 + j] = (short)f2bf(__uint_as_float(b[j])); }
        frag[kc] = v;
      }
    }
  }

  if (gru == 0){   // fp32 carry init into hold[0] (2 waves cover 16x32)
    #pragma unroll
    for (int r = 0; r < 4; ++r){
      const size_t si = (size_t)(d0 + quad * 4 + r) * 256 + col;
      hold[0][(quad * 4 + r) * 33 + colw] =
          fdt ? bf2f(((const unsigned short*)hinit)[si]) : ((const float*)hinit)[si];
    }
  }

  int ef[4];
  {
    const int base = d0 + quad * 4;
    if (efmt == 0){      for (int r = 0; r < 4; ++r) ef[r] = edges[base + r] != 0; }
    else if (efmt == 1){ for (int r = 0; r < 4; ++r) ef[r] = ((const int*)edges)[base + r] != 0; }
    else if (efmt == 3){ for (int r = 0; r < 4; ++r) ef[r] = ((const unsigned short*)edges)[base + r] != 0; }
    else {               for (int r = 0; r < 4; ++r) ef[r] = ((const float*)edges)[base + r] != 0.0f; }
  }
  __syncthreads();   // ONLY loop-relevant barrier: hold[0] init visible to all waves

  uint32_t* flgG = flg + G * 32;
  uint32_t sPk[4] = {0, 0, 0, 0};
  float    sCd[4] = {0, 0, 0, 0};
  int      sMn[4] = {0, 0, 0, 0};

  // ---------------- main recurrence (no intra-block barriers) ----------------
  for (int t = 0; t < TT; ++t){
    // ---- deferred out[t-1] stores (fire-and-forget; ack during poll) ----
    if (t > 0){
      #pragma unroll
      for (int r = 0; r < 4; ++r){
        const int row = quad * 4 + r;
        if (fdt){
          if (sMn[r] && !(lane & 1)){
            unsigned short* o16 = (unsigned short*)out;
            *(uint32_t*)(o16 + (size_t)(t - 1) * 131072 + (size_t)(d0 + row) * 256 + col) = sPk[r];
          }
        } else {
          if (sMn[r]){
            float* o32 = (float*)out;
            o32[(size_t)(t - 1) * 131072 + (size_t)(d0 + row) * 256 + col] = sCd[r];
          }
        }
      }
    }

    // ---- poll 32 flags >= t, then gather h_t A-frags straight into registers ----
    if (t > 0){
      const uint32_t target = (uint32_t)t;
      const uint32_t* fp = flgG + (lane & 31);
      uint32_t fv = __hip_atomic_load(fp, __ATOMIC_RELAXED, __HIP_MEMORY_SCOPE_AGENT);
      int guard = 0;
      while (__ballot(fv < target) != 0ull){
        __builtin_amdgcn_s_sleep(1);
        fv = __hip_atomic_load(fp, __ATOMIC_RELAXED, __HIP_MEMORY_SCOPE_AGENT);
        if (++guard > GUARD_ITERS) break;   // bounded: broken sync -> garbage, not hang
      }
      __atomic_signal_fence(__ATOMIC_SEQ_CST);
      const uint64_t* srcq = (const uint64_t*)xbp
          + ((((size_t)(t & 1) * 512 + myrow) * 256) >> 2) + quad * 2;
      #pragma unroll
      for (int kc = 0; kc < 8; ++kc){
        FragU f;
        f.q[0] = __hip_atomic_load(srcq + kc * 8 + 0, __ATOMIC_RELAXED, __HIP_MEMORY_SCOPE_AGENT);
        f.q[1] = __hip_atomic_load(srcq + kc * 8 + 1, __ATOMIC_RELAXED, __HIP_MEMORY_SCOPE_AGENT);
        frag[kc] = f.v;
      }
    }

    // ---- fp32 carry read (after poll: pair-wave's write is flag-ordered) ----
    float hold4[4];
    #pragma unroll
    for (int r = 0; r < 4; ++r) hold4[r] = hold[t & 1][(quad * 4 + r) * 33 + colw];

    // ---- hh-GEMM from register frags ----
    float4v aH[3];
    #pragma unroll
    for (int ga = 0; ga < 3; ++ga) aH[ga] = splat4(bH[ga]);
    #pragma unroll
    for (int kc = 0; kc < 8; ++kc){
      #pragma unroll
      for (int ga = 0; ga < 3; ++ga)
        aH[ga] = __builtin_amdgcn_mfma_f32_16x16x32_bf16(frag[kc], wH[ga][kc], aH[ga], 0, 0, 0);
    }

    // ---- gates ----
    float cand[4]; int mine[4];
    #pragma unroll
    for (int r = 0; r < 4; ++r){
      const float pr = gi[0][r] + aH[0][r];
      const float pz = gi[1][r] + aH[1][r];
      const float R  = 1.0f / (1.0f + exp2f(-1.4426950408889634f * pr));
      const float Z  = 1.0f / (1.0f + exp2f(-1.4426950408889634f * pz));
      float ag = gi[2][r] + R * aH[2][r];
      ag = fminf(30.0f, fmaxf(-30.0f, ag));
      const float ex = exp2f(-2.8853900817779268f * ag);
      const float N  = (1.0f - ex) / (1.0f + ex);
      cand[r] = N + Z * (hold4[r] - N);
      mine[r] = ((ef[r] != 0) == (gru == 0)) ? 1 : 0;   // edge -> child GRU
    }

    // ---- writes: hold[buf], exchange slice, save out regs ----
    const int buf = (t + 1) & 1;
    #pragma unroll
    for (int r = 0; r < 4; ++r){
      const int row = quad * 4 + r;
      if (mine[r]) hold[buf][row * 33 + colw] = cand[r];
      const uint32_t bb = (uint32_t)f2bf(cand[r]);
      const uint32_t ob = (uint32_t)__shfl_xor((int)bb, 1, 64);
      const uint32_t pk = bb | (ob << 16);
      sPk[r] = pk; sCd[r] = cand[r]; sMn[r] = mine[r];
      if (t < TT - 1 && mine[r] && !(lane & 1)){
        uint32_t* xp = (uint32_t*)xbp + ((size_t)buf * 512 + d0 + row) * 128 + (col >> 1);
        __hip_atomic_store(xp, pk, __ATOMIC_RELAXED, __HIP_MEMORY_SCOPE_AGENT);
      }
    }

    if (t < TT - 1){
      // ---- publish: drain ALL this wave's mem ops (vm: exchange; lgkm: hold), flag ----
      __atomic_signal_fence(__ATOMIC_SEQ_CST);
      __builtin_amdgcn_s_waitcnt(0);
      __atomic_signal_fence(__ATOMIC_SEQ_CST);
      if (lane == 0)
        __hip_atomic_store(flgG + cs * 4 + wv, (uint32_t)(t + 1),
                           __ATOMIC_RELAXED, __HIP_MEMORY_SCOPE_AGENT);

      // ---- off-chain: x_{t+1} A-frags + ih-GEMM -> gi, edges_{t+1} ----
      {
        const int nd = nodes[(t + 1) * DDIM + myrow];
        if (fdt){
          const unsigned short* p16 = (const unsigned short*)emb + (size_t)nd * 256 + quad * 8;
          #pragma unroll
          for (int kc = 0; kc < 8; ++kc) frag[kc] = *(const short8*)(p16 + kc * 32);
        } else {
          const float* p32 = (const float*)emb + (size_t)nd * 256 + quad * 8;
          #pragma unroll
          for (int kc = 0; kc < 8; ++kc){
            uint4v a = *(const uint4v*)(p32 + kc * 32);
            uint4v b = *(const uint4v*)(p32 + kc * 32 + 4);
            short8 v;
            #pragma unroll
            for (int j = 0; j < 4; ++j){ v[j] = (short)f2bf(__uint_as_float(a[j]));
                                         v[4 + j] = (short)f2bf(__uint_as_float(b[j])); }
            frag[kc] = v;
          }
        }
        #pragma unroll
        for (int ga = 0; ga < 3; ++ga) gi[ga] = splat4(bI[ga]);
        #pragma unroll
        for (int kc = 0; kc < 8; ++kc){
          #pragma unroll
          for (int ga = 0; ga < 3; ++ga)
            gi[ga] = __builtin_amdgcn_mfma_f32_16x16x32_bf16(frag[kc], wI[ga][kc], gi[ga], 0, 0, 0);
        }
        const int eb = (t + 1) * DDIM + d0 + quad * 4;
        if (efmt == 0){      for (int r2 = 0; r2 < 4; ++r2) ef[r2] = edges[eb + r2] != 0; }
        else if (efmt == 1){ for (int r2 = 0; r2 < 4; ++r2) ef[r2] = ((const int*)edges)[eb + r2] != 0; }
        else if (efmt == 3){ for (int r2 = 0; r2 < 4; ++r2) ef[r2] = ((const unsigned short*)edges)[eb + r2] != 0; }
        else {               for (int r2 = 0; r2 < 4; ++r2) ef[r2] = ((const float*)edges)[eb + r2] != 0.0f; }
      }
    }
  }

  // ---- epilogue: out[255] + duplicated h_final slab from saved regs ----
  #pragma unroll
  for (int r = 0; r < 4; ++r){
    const int row = quad * 4 + r;
    if (fdt){
      if (sMn[r] && !(lane & 1)){
        unsigned short* o16 = (unsigned short*)out;
        *(uint32_t*)(o16 + (size_t)255 * 131072 + (size_t)(d0 + row) * 256 + col) = sPk[r];
        *(uint32_t*)(o16 + (size_t)256 * 131072 + (size_t)(d0 + row) * 256 + col) = sPk[r];
      }
    } else {
      if (sMn[r]){
        float* o32 = (float*)out;
        o32[(size_t)255 * 131072 + (size_t)(d0 + row) * 256 + col] = sCd[r];
        o32[(size_t)256 * 131072 + (size_t)(d0 + row) * 256 + col] = sCd[r];
      }
    }
  }
}

extern "C" void kernel_launch(void* const* d_in, const int* in_sizes, int n_in,
                              void* d_out, int out_size, void* d_ws, size_t ws_size,
                              hipStream_t stream)
{
  const int*           nodes = (const int*)d_in[0];
  const unsigned char* edges = (const unsigned char*)d_in[1];
  const unsigned char* hinit = (const unsigned char*)d_in[2];
  const unsigned char* emb   = (const unsigned char*)d_in[3];
  const unsigned char* cWih  = (const unsigned char*)d_in[4];
  const unsigned char* cWhh  = (const unsigned char*)d_in[5];
  const unsigned char* cbih  = (const unsigned char*)d_in[6];
  const unsigned char* cbhh  = (const unsigned char*)d_in[7];
  const unsigned char* sWih  = (const unsigned char*)d_in[8];
  const unsigned char* sWhh  = (const unsigned char*)d_in[9];
  const unsigned char* sbih  = (const unsigned char*)d_in[10];
  const unsigned char* sbhh  = (const unsigned char*)d_in[11];
  (void)in_sizes; (void)n_in; (void)out_size; (void)ws_size;

  // zero flag region (ws re-poisoned before every launch)
  hipMemsetAsync(d_ws, 0, 8192, stream);

  treernn_main<<<dim3(256), dim3(256), 0, stream>>>(
      nodes, edges, hinit, emb, cWih, cWhh, cbih, cbhh, sWih, sWhh, sbih, sbhh,
      (unsigned char*)d_out, (unsigned char*)d_ws);
}